// Round 1
// baseline (500.205 us; speedup 1.0000x reference)
//
#include <hip/hip_runtime.h>

typedef float f32x4 __attribute__((ext_vector_type(4)));
typedef __bf16 bf16x8 __attribute__((ext_vector_type(8)));
typedef unsigned short u16x8 __attribute__((ext_vector_type(8)));

__device__ __forceinline__ unsigned short f2bf(float f) {
  union { float f; unsigned int u; } v; v.f = f;
  unsigned int u = v.u;
  unsigned int r = (u + 0x7FFFu + ((u >> 16) & 1u)) >> 16;  // RNE
  return (unsigned short)r;
}

// ---------------- cast x (f32 -> bf16), 8 elems/thread ----------------
__global__ void k_cast_bf16(const float* __restrict__ in,
                            unsigned short* __restrict__ out, int n8) {
  int i = blockIdx.x * blockDim.x + threadIdx.x;
  if (i >= n8) return;
  const f32x4* p = (const f32x4*)in;
  f32x4 a = p[2 * i], b = p[2 * i + 1];
  u16x8 o;
  o[0] = f2bf(a[0]); o[1] = f2bf(a[1]); o[2] = f2bf(a[2]); o[3] = f2bf(a[3]);
  o[4] = f2bf(b[0]); o[5] = f2bf(b[1]); o[6] = f2bf(b[2]); o[7] = f2bf(b[3]);
  ((u16x8*)out)[i] = o;
}

// -------- Bw[o][e*16+r] = coeffs[e]*scales[e]*Bf[e][o][r], bf16 --------
__global__ void k_build_bw(const float* __restrict__ Bf,
                           const float* __restrict__ coeffs,
                           const float* __restrict__ scales,
                           unsigned short* __restrict__ bw) {
  int t = blockIdx.x * 256 + threadIdx.x;   // 4096*256 total
  int o = t >> 8, k = t & 255, e = k >> 4, r = k & 15;
  float v = coeffs[e] * scales[e] * Bf[((size_t)e * 4096 + o) * 16 + r];
  bw[t] = f2bf(v);
}

// -------- At[d][e*16+r] = A[e][r][d], bf16, via LDS transpose --------
__global__ void k_build_at(const float* __restrict__ A,
                           unsigned short* __restrict__ at) {
  __shared__ float tile[64][65];
  int kt = blockIdx.x * 64, dt = blockIdx.y * 64;
  int tx = threadIdx.x & 63, ty = threadIdx.x >> 6;  // ty 0..3
#pragma unroll
  for (int j = 0; j < 64; j += 4)
    tile[ty + j][tx] = A[(size_t)(kt + ty + j) * 4096 + dt + tx];
  __syncthreads();
#pragma unroll
  for (int j = 0; j < 64; j += 4)
    at[(size_t)(dt + ty + j) * 256 + kt + tx] = f2bf(tile[tx][ty + j]);
}

// ---------------- m97-structure bf16 GEMM, C = A * B^T ----------------
// A: [M_][K_] bf16 row-major.  B: [N_][K_] bf16 row-major (B^T form).
// PREP: out_bf16[m][n] = acc + extraW[m][n]   (extra = W, f32)
// !PREP: out_f32[m][n] = acc + extra[n]       (extra = bias, f32)
template <int M_, int N_, int K_, bool PREP>
__global__ __launch_bounds__(256) void k_gemm_bt(
    const unsigned short* __restrict__ Abuf,
    const unsigned short* __restrict__ Bbuf,
    const float* __restrict__ extra,
    float* __restrict__ outF,
    unsigned short* __restrict__ outB) {
  constexpr int NBN = N_ / 128;
  constexpr int NWG = (M_ / 128) * NBN;
  static_assert(NWG % 8 == 0, "bijective xcd swizzle needs nwg%8==0");

  // XCD-aware swizzle: contiguous chunk of output tiles per XCD
  const int bid = blockIdx.x;
  const int swz = (bid & 7) * (NWG / 8) + (bid >> 3);
  const int bm = swz / NBN, bn = swz % NBN;

  __shared__ unsigned short ldsA[128 * 64];
  __shared__ unsigned short ldsB[128 * 64];

  const int t = threadIdx.x, w = t >> 6, l = t & 63;
  const int wr = w >> 1, wc = w & 1;  // 2x2 waves, 64x64 out each

  f32x4 acc[4][4] = {};

  const int m0 = bm * 128, n0 = bn * 128;
  const int srow = w * 8 + (l >> 3);   // staging row within tile (+i*32)
  const int scol = (l & 7) * 8;        // staging col (8 bf16 = 16B)
  const unsigned short* gA = Abuf + (size_t)(m0 + srow) * K_ + scol;
  const unsigned short* gB = Bbuf + (size_t)(n0 + srow) * K_ + scol;

  for (int kt = 0; kt < K_; kt += 64) {
    // stage A,B tiles: global -> LDS direct, 16B/lane, linear layout
#pragma unroll
    for (int i = 0; i < 4; ++i) {
      __builtin_amdgcn_global_load_lds(
          (__attribute__((address_space(1))) void*)(gA + (size_t)i * 32 * K_ + kt),
          (__attribute__((address_space(3))) void*)(ldsA + i * 2048 + w * 512),
          16, 0, 0);
      __builtin_amdgcn_global_load_lds(
          (__attribute__((address_space(1))) void*)(gB + (size_t)i * 32 * K_ + kt),
          (__attribute__((address_space(3))) void*)(ldsB + i * 2048 + w * 512),
          16, 0, 0);
    }
    __syncthreads();  // compiler drains vmcnt(0) before s_barrier

#pragma unroll
    for (int kk = 0; kk < 2; ++kk) {
      const int col = kk * 32 + (l >> 4) * 8;       // 8 consecutive k per lane
      const int arow = wr * 64 + (l & 15);
      const int brow = wc * 64 + (l & 15);
      bf16x8 af[4], bfv[4];
#pragma unroll
      for (int mi = 0; mi < 4; ++mi)
        af[mi] = *(const bf16x8*)&ldsA[(arow + mi * 16) * 64 + col];
#pragma unroll
      for (int ni = 0; ni < 4; ++ni)
        bfv[ni] = *(const bf16x8*)&ldsB[(brow + ni * 16) * 64 + col];
#pragma unroll
      for (int mi = 0; mi < 4; ++mi)
#pragma unroll
        for (int ni = 0; ni < 4; ++ni)
          acc[mi][ni] = __builtin_amdgcn_mfma_f32_16x16x32_bf16(
              af[mi], bfv[ni], acc[mi][ni], 0, 0, 0);
    }
    __syncthreads();
  }

  // C/D layout (m89-verified): col = lane&15, row = (lane>>4)*4 + reg
  const int mrow0 = m0 + wr * 64 + (l >> 4) * 4;
  const int ncol0 = n0 + wc * 64 + (l & 15);

  if constexpr (PREP) {
#pragma unroll
    for (int mi = 0; mi < 4; ++mi)
#pragma unroll
      for (int r = 0; r < 4; ++r) {
        const int m = mrow0 + mi * 16 + r;
#pragma unroll
        for (int ni = 0; ni < 4; ++ni) {
          const int n = ncol0 + ni * 16;
          outB[(size_t)m * N_ + n] = f2bf(acc[mi][ni][r] + extra[(size_t)m * N_ + n]);
        }
      }
  } else {
#pragma unroll
    for (int ni = 0; ni < 4; ++ni) {
      const int n = ncol0 + ni * 16;
      const float bv = extra[n];
#pragma unroll
      for (int mi = 0; mi < 4; ++mi)
#pragma unroll
        for (int r = 0; r < 4; ++r) {
          const int m = mrow0 + mi * 16 + r;
          outF[(size_t)m * N_ + n] = acc[mi][ni][r] + bv;
        }
    }
  }
}

extern "C" void kernel_launch(void* const* d_in, const int* in_sizes, int n_in,
                              void* d_out, int out_size, void* d_ws, size_t ws_size,
                              hipStream_t stream) {
  const float* x      = (const float*)d_in[0];  // [4,2048,4096] -> [8192][4096]
  const float* W      = (const float*)d_in[1];  // [4096][4096] (O,D)
  const float* bias   = (const float*)d_in[2];  // [4096]
  const float* A      = (const float*)d_in[3];  // [16][16][4096]
  const float* Bf     = (const float*)d_in[4];  // [16][4096][16]
  const float* coeffs = (const float*)d_in[5];  // [16]
  const float* scales = (const float*)d_in[6];  // [16]
  float* out = (float*)d_out;                   // [8192][4096] f32

  char* ws = (char*)d_ws;
  unsigned short* xb   = (unsigned short*)(ws);                         // 64 MiB
  unsigned short* weff = (unsigned short*)(ws + 67108864);              // 32 MiB
  unsigned short* bw   = (unsigned short*)(ws + 67108864 + 33554432);   //  2 MiB
  unsigned short* at   = (unsigned short*)(ws + 67108864 + 33554432 + 2097152); // 2 MiB

  // 1) x -> bf16
  k_cast_bf16<<<16384, 256, 0, stream>>>(x, xb, (8192 * 4096) / 8);
  // 2) LoRA factor repack (bf16): Bw [4096][256], At [4096][256]
  k_build_bw<<<4096, 256, 0, stream>>>(Bf, coeffs, scales, bw);
  k_build_at<<<dim3(4, 64), 256, 0, stream>>>(A, at);
  // 3) W_eff = W + Bw @ At^T   (bf16 out, K=256)
  k_gemm_bt<4096, 4096, 256, true><<<1024, 256, 0, stream>>>(bw, at, W, nullptr, weff);
  // 4) out = xb @ W_eff^T + bias   (f32 out, K=4096)
  k_gemm_bt<8192, 4096, 4096, false><<<2048, 256, 0, stream>>>(xb, weff, bias, out, nullptr);
}

// Round 2
// 350.571 us; speedup vs baseline: 1.4268x; 1.4268x over previous
//
#include <hip/hip_runtime.h>

typedef float f32x4 __attribute__((ext_vector_type(4)));
typedef __bf16 bf16x8 __attribute__((ext_vector_type(8)));
typedef unsigned short u16x8 __attribute__((ext_vector_type(8)));

__device__ __forceinline__ unsigned short f2bf(float f) {
  union { float f; unsigned int u; } v; v.f = f;
  unsigned int u = v.u;
  unsigned int r = (u + 0x7FFFu + ((u >> 16) & 1u)) >> 16;  // RNE
  return (unsigned short)r;
}

// ---------------- cast x (f32 -> bf16), 8 elems/thread ----------------
__global__ void k_cast_bf16(const float* __restrict__ in,
                            unsigned short* __restrict__ out, int n8) {
  int i = blockIdx.x * blockDim.x + threadIdx.x;
  if (i >= n8) return;
  const f32x4* p = (const f32x4*)in;
  f32x4 a = p[2 * i], b = p[2 * i + 1];
  u16x8 o;
  o[0] = f2bf(a[0]); o[1] = f2bf(a[1]); o[2] = f2bf(a[2]); o[3] = f2bf(a[3]);
  o[4] = f2bf(b[0]); o[5] = f2bf(b[1]); o[6] = f2bf(b[2]); o[7] = f2bf(b[3]);
  ((u16x8*)out)[i] = o;
}

// -------- Bw[o][e*16+r] = coeffs[e]*scales[e]*Bf[e][o][r], bf16 --------
__global__ void k_build_bw(const float* __restrict__ Bf,
                           const float* __restrict__ coeffs,
                           const float* __restrict__ scales,
                           unsigned short* __restrict__ bw) {
  int t = blockIdx.x * 256 + threadIdx.x;
  int o = t >> 8, k = t & 255, e = k >> 4, r = k & 15;
  float v = coeffs[e] * scales[e] * Bf[((size_t)e * 4096 + o) * 16 + r];
  bw[t] = f2bf(v);
}

// -------- At[d][e*16+r] = A[e][r][d], bf16, via LDS transpose --------
__global__ void k_build_at(const float* __restrict__ A,
                           unsigned short* __restrict__ at) {
  __shared__ float tile[64][65];
  int kt = blockIdx.x * 64, dt = blockIdx.y * 64;
  int tx = threadIdx.x & 63, ty = threadIdx.x >> 6;
#pragma unroll
  for (int j = 0; j < 64; j += 4)
    tile[ty + j][tx] = A[(size_t)(kt + ty + j) * 4096 + dt + tx];
  __syncthreads();
#pragma unroll
  for (int j = 0; j < 64; j += 4)
    at[(size_t)(dt + ty + j) * 256 + kt + tx] = f2bf(tile[tx][ty + j]);
}

// ------------- prep GEMM (m97 structure), W_eff = Bw @ At^T + W -------------
template <int M_, int N_, int K_>
__global__ __launch_bounds__(256) void k_gemm_prep(
    const unsigned short* __restrict__ Abuf,
    const unsigned short* __restrict__ Bbuf,
    const float* __restrict__ Wadd,
    unsigned short* __restrict__ outB) {
  constexpr int NBN = N_ / 128;
  constexpr int NWG = (M_ / 128) * NBN;
  const int bid = blockIdx.x;
  const int swz = (bid & 7) * (NWG / 8) + (bid >> 3);
  const int bm = swz / NBN, bn = swz % NBN;

  __shared__ unsigned short ldsA[128 * 64];
  __shared__ unsigned short ldsB[128 * 64];

  const int t = threadIdx.x, w = t >> 6, l = t & 63;
  const int wr = w >> 1, wc = w & 1;

  f32x4 acc[4][4] = {};
  const int m0 = bm * 128, n0 = bn * 128;
  const int srow = w * 8 + (l >> 3);
  const int scol = (l & 7) * 8;
  const unsigned short* gA = Abuf + (size_t)(m0 + srow) * K_ + scol;
  const unsigned short* gB = Bbuf + (size_t)(n0 + srow) * K_ + scol;

  for (int kt = 0; kt < K_; kt += 64) {
#pragma unroll
    for (int i = 0; i < 4; ++i) {
      __builtin_amdgcn_global_load_lds(
          (__attribute__((address_space(1))) void*)(gA + (size_t)i * 32 * K_ + kt),
          (__attribute__((address_space(3))) void*)(ldsA + i * 2048 + w * 512), 16, 0, 0);
      __builtin_amdgcn_global_load_lds(
          (__attribute__((address_space(1))) void*)(gB + (size_t)i * 32 * K_ + kt),
          (__attribute__((address_space(3))) void*)(ldsB + i * 2048 + w * 512), 16, 0, 0);
    }
    __syncthreads();
#pragma unroll
    for (int kk = 0; kk < 2; ++kk) {
      const int col = kk * 32 + (l >> 4) * 8;
      const int arow = wr * 64 + (l & 15);
      const int brow = wc * 64 + (l & 15);
      bf16x8 af[4], bfv[4];
#pragma unroll
      for (int mi = 0; mi < 4; ++mi)
        af[mi] = *(const bf16x8*)&ldsA[(arow + mi * 16) * 64 + col];
#pragma unroll
      for (int ni = 0; ni < 4; ++ni)
        bfv[ni] = *(const bf16x8*)&ldsB[(brow + ni * 16) * 64 + col];
#pragma unroll
      for (int mi = 0; mi < 4; ++mi)
#pragma unroll
        for (int ni = 0; ni < 4; ++ni)
          acc[mi][ni] = __builtin_amdgcn_mfma_f32_16x16x32_bf16(
              af[mi], bfv[ni], acc[mi][ni], 0, 0, 0);
    }
    __syncthreads();
  }

  const int mrow0 = m0 + wr * 64 + (l >> 4) * 4;
  const int ncol0 = n0 + wc * 64 + (l & 15);
#pragma unroll
  for (int mi = 0; mi < 4; ++mi)
#pragma unroll
    for (int r = 0; r < 4; ++r) {
      const int m = mrow0 + mi * 16 + r;
#pragma unroll
      for (int ni = 0; ni < 4; ++ni) {
        const int n = ncol0 + ni * 16;
        outB[(size_t)m * N_ + n] = f2bf(acc[mi][ni][r] + Wadd[(size_t)m * N_ + n]);
      }
    }
}

// ============ main GEMM: 256x256 tile, BK=64, 8-phase, out = A*B^T + bias ============
// A [M_][K_] bf16, B [N_][K_] bf16, out f32.
// LDS 128 KiB: buf b at b*65536; A half [256][64] at +0, B at +32768.
// XOR swizzle: logical (row, 16B-block kb) stored at physical block kb^(row&7);
// staging keeps LDS dest linear and pre-swizzles the GLOBAL source (rule #21).
template <int M_, int N_, int K_>
__global__ __launch_bounds__(512, 2) void k_gemm256(
    const unsigned short* __restrict__ Abuf,
    const unsigned short* __restrict__ Bbuf,
    const float* __restrict__ bias,
    float* __restrict__ outF) {
  constexpr int NBN = N_ / 256;
  constexpr int NWG = (M_ / 256) * NBN;
  constexpr int NKT = K_ / 64;
  static_assert(NWG % 8 == 0, "bijective xcd swizzle");
  static_assert(NKT % 2 == 0, "even K-tiles");

  const int bid = blockIdx.x;
  const int swz = (bid & 7) * (NWG / 8) + (bid >> 3);
  const int bm = swz / NBN, bn = swz % NBN;
  const int m0 = bm * 256, n0 = bn * 256;

  __shared__ __attribute__((aligned(128))) unsigned short lds[65536];  // 128 KiB
  char* ldsb = (char*)lds;

  const int t = threadIdx.x, w = t >> 6, l = t & 63;
  const int wr = w >> 2, wc = w & 3;  // 2 M-waves x 4 N-waves; per-wave out 128x64
  const int lan7 = l & 7;

  // staging: instr p covers rows p*64..p*64+63; wave w writes rows w*8..w*8+7,
  // lane lands linearly (row = w*8 + l/8, 16B block = l%8); fetch pre-swizzled
  // global block (l%8)^(l/8).
  const int srow = w * 8 + (l >> 3);
  const int scol = (lan7 ^ (l >> 3)) * 8;
  const unsigned short* gA = Abuf + (size_t)(m0 + srow) * K_ + scol;
  const unsigned short* gB = Bbuf + (size_t)(n0 + srow) * K_ + scol;
  const int sA = w * 1024;          // + p*8192 + buf*65536
  const int sB = 32768 + w * 1024;

  // fragment reads: A row = wr*128 + mi*16 + (l&15); kb = kk*4 + (l>>4)
  const int raBase = (wr * 128 + (l & 15)) * 128;
  const int rbBase = 32768 + (wc * 64 + (l & 15)) * 128;
  const int kswz = l >> 4;

  f32x4 acc[8][4] = {};
  bf16x8 af[4], bb[4];

#define STAGE(p, bsel, ktn)                                                              \
  do {                                                                                   \
    __builtin_amdgcn_global_load_lds(                                                    \
        (__attribute__((address_space(1))) void*)(gA + (size_t)(p) * 64 * K_ + (ktn)),   \
        (__attribute__((address_space(3))) void*)(ldsb + (bsel) * 65536 + (p) * 8192 + sA), \
        16, 0, 0);                                                                       \
    __builtin_amdgcn_global_load_lds(                                                    \
        (__attribute__((address_space(1))) void*)(gB + (size_t)(p) * 64 * K_ + (ktn)),   \
        (__attribute__((address_space(3))) void*)(ldsb + (bsel) * 65536 + (p) * 8192 + sB), \
        16, 0, 0);                                                                       \
  } while (0)

#define RDA(mi, kk, bsel) \
  (*(const bf16x8*)(ldsb + (bsel) * 65536 + raBase + (mi) * 2048 + ((((kk)*4 + kswz) ^ lan7) << 4)))
#define RDB(ni, kk, bsel) \
  (*(const bf16x8*)(ldsb + (bsel) * 65536 + rbBase + (ni) * 2048 + ((((kk)*4 + kswz) ^ lan7) << 4)))

#define LOADA(mb, kk, bsel)                                                   \
  do {                                                                        \
    af[0] = RDA((mb) + 0, kk, bsel); af[1] = RDA((mb) + 1, kk, bsel);         \
    af[2] = RDA((mb) + 2, kk, bsel); af[3] = RDA((mb) + 3, kk, bsel);         \
  } while (0)
#define LOADB(kk, bsel)                                                       \
  do {                                                                        \
    bb[0] = RDB(0, kk, bsel); bb[1] = RDB(1, kk, bsel);                       \
    bb[2] = RDB(2, kk, bsel); bb[3] = RDB(3, kk, bsel);                       \
  } while (0)
#define MFMA16(mb)                                                            \
  do {                                                                        \
    _Pragma("unroll") for (int i_ = 0; i_ < 4; ++i_) {                        \
      _Pragma("unroll") for (int j_ = 0; j_ < 4; ++j_)                        \
          acc[(mb) + i_][j_] = __builtin_amdgcn_mfma_f32_16x16x32_bf16(       \
              af[i_], bb[j_], acc[(mb) + i_][j_], 0, 0, 0);                   \
    }                                                                         \
  } while (0)

  // prologue: stage K-tile 0 into buf 0 (8 loads, stay in flight)
#pragma unroll
  for (int p = 0; p < 4; ++p) STAGE(p, 0, 0);

  auto ktile = [&](int kti, int b) {
    const int nb = b ^ 1;
    const int ktn = (kti + 1) * 64;
    const bool more = (kti + 1) < NKT;

    // -- phase 0: mi 0-3, kk 0 --
    if (more) STAGE(0, nb, ktn);
    if (more) { asm volatile("s_waitcnt vmcnt(2)" ::: "memory"); }
    else      { asm volatile("s_waitcnt vmcnt(0)" ::: "memory"); }
    __builtin_amdgcn_s_barrier();
    asm volatile("" ::: "memory");
    LOADA(0, 0, b); LOADB(0, b);
    __builtin_amdgcn_s_setprio(1);
    MFMA16(0);
    __builtin_amdgcn_s_setprio(0);
    __builtin_amdgcn_s_barrier();

    // -- phase 1: mi 4-7, kk 0 (B frags reused) --
    LOADA(4, 0, b);
    if (more) STAGE(1, nb, ktn);
    __builtin_amdgcn_s_barrier();
    __builtin_amdgcn_s_setprio(1);
    MFMA16(4);
    __builtin_amdgcn_s_setprio(0);
    __builtin_amdgcn_s_barrier();

    // -- phase 2: mi 0-3, kk 1 --
    LOADA(0, 1, b); LOADB(1, b);
    if (more) STAGE(2, nb, ktn);
    __builtin_amdgcn_s_barrier();
    __builtin_amdgcn_s_setprio(1);
    MFMA16(0);
    __builtin_amdgcn_s_setprio(0);
    __builtin_amdgcn_s_barrier();

    // -- phase 3: mi 4-7, kk 1 --
    LOADA(4, 1, b);
    if (more) STAGE(3, nb, ktn);
    __builtin_amdgcn_s_barrier();
    __builtin_amdgcn_s_setprio(1);
    MFMA16(4);
    __builtin_amdgcn_s_setprio(0);
    __builtin_amdgcn_s_barrier();
  };

  for (int kti = 0; kti < NKT; kti += 2) {
    ktile(kti, 0);
    ktile(kti + 1, 1);
  }

  // epilogue: C/D layout col = lane&15, row = (lane>>4)*4 + reg
#pragma unroll
  for (int ni = 0; ni < 4; ++ni) {
    const int n = n0 + wc * 64 + ni * 16 + (l & 15);
    const float bv = bias[n];
#pragma unroll
    for (int mi = 0; mi < 8; ++mi) {
      const int m = m0 + wr * 128 + mi * 16 + (l >> 4) * 4;
#pragma unroll
      for (int r = 0; r < 4; ++r)
        outF[(size_t)(m + r) * N_ + n] = acc[mi][ni][r] + bv;
    }
  }
#undef STAGE
#undef RDA
#undef RDB
#undef LOADA
#undef LOADB
#undef MFMA16
}

extern "C" void kernel_launch(void* const* d_in, const int* in_sizes, int n_in,
                              void* d_out, int out_size, void* d_ws, size_t ws_size,
                              hipStream_t stream) {
  const float* x      = (const float*)d_in[0];
  const float* W      = (const float*)d_in[1];
  const float* bias   = (const float*)d_in[2];
  const float* A      = (const float*)d_in[3];
  const float* Bf     = (const float*)d_in[4];
  const float* coeffs = (const float*)d_in[5];
  const float* scales = (const float*)d_in[6];
  float* out = (float*)d_out;

  char* ws = (char*)d_ws;
  unsigned short* xb   = (unsigned short*)(ws);
  unsigned short* weff = (unsigned short*)(ws + 67108864);
  unsigned short* bw   = (unsigned short*)(ws + 67108864 + 33554432);
  unsigned short* at   = (unsigned short*)(ws + 67108864 + 33554432 + 2097152);

  k_cast_bf16<<<16384, 256, 0, stream>>>(x, xb, (8192 * 4096) / 8);
  k_build_bw<<<4096, 256, 0, stream>>>(Bf, coeffs, scales, bw);
  k_build_at<<<dim3(4, 64), 256, 0, stream>>>(A, at);
  k_gemm_prep<4096, 4096, 256><<<1024, 256, 0, stream>>>(bw, at, W, weff);
  k_gemm256<8192, 4096, 4096><<<512, 512, 0, stream>>>(xb, weff, bias, out);
}